// Round 1
// 286.368 us; speedup vs baseline: 1.2168x; 1.2168x over previous
//
#include <hip/hip_runtime.h>

// GCN: 4x GCNConv(128->128, sym norm, self-loops) + FC(128->32) + global mean pool.
// R12->R13: THE NETWORK IS LINEAR (no activation between GCNConv layers). Collapse:
//   y = A^4 x Wc + A^3 1 c1^T + A^2 1 c2^T + A 1 c3^T + 1 c4^T
//     = A(A(A(A z + 1c1) + 1c2) + 1c3) + 1c4,  z = x @ Wc,
// Wc = W1W2W3W4 fcW (128x32), c_i = suffix-propagated biases (32-vec, added per agg
// epilogue exactly like the old per-layer bias). So: ONE 128->32 GEMM + FOUR 32-dim
// aggregations. Gather traffic/agg: 256B -> 64B per edge (4x), gather table 12.8MB ->
// 3.2MB (fits per-XCD 4MiB L2). Weight collapse = single-block fp32 chain (~4us).

#define N_NODES 50000
#define N_EDGES 600000
#define D 128
#define D_OUT 32
#define N_GRAPHS 64
#define SCAN_B 1024
#define N_SCAN_BLOCKS 49          // ceil(50000/1024)
#define GEMM_BLOCKS 782           // ceil(50000/64)
#define AGG_GRID 12500            // 50000/4

typedef short short8 __attribute__((ext_vector_type(8)));
typedef float floatx4 __attribute__((ext_vector_type(4)));

__device__ inline unsigned bf16rne(float a) {
    unsigned u = __float_as_uint(a);
    return (u + 0x7fffu + ((u >> 16) & 1u)) >> 16;
}
__device__ inline unsigned bf16pair(float a, float b) {
    return bf16rne(a) | (bf16rne(b) << 16);
}

// ---------------- graph preprocessing ----------------

__global__ void hist_kernel(const int* __restrict__ dst, int* __restrict__ indeg) {
    int e = blockIdx.x * blockDim.x + threadIdx.x;
    if (e < N_EDGES) atomicAdd(&indeg[dst[e]], 1);
}

// Weight collapse: suffix products S3=W4@fcW, S2=W3@S3, S1=W2@S2, Wc=W1@S1 (all fp32),
// bias constants c1=b1@S1, c2=b2@S2, c3=b3@S3, c4=b4@fcW+fcb. WcT stored bf16 [32][128]
// (k-contiguous per output col, the MFMA B layout the gemm expects).
__global__ __launch_bounds__(1024) void collapse_kernel(
        const float* __restrict__ W1, const float* __restrict__ W2,
        const float* __restrict__ W3, const float* __restrict__ W4,
        const float* __restrict__ fcW, const float* __restrict__ fcb,
        const float* __restrict__ b1, const float* __restrict__ b2,
        const float* __restrict__ b3, const float* __restrict__ b4,
        unsigned short* __restrict__ WcT, float* __restrict__ cvec) {
    __shared__ float Sa[128][33];  // +1 pad: conflict-free column writes
    __shared__ float Sb[128][33];
    int t = threadIdx.x;
    int i = t >> 3;          // 0..127 output row
    int j4 = (t & 7) * 4;    // output col group of 4

    for (int idx = t; idx < 4096; idx += 1024) Sa[idx >> 5][idx & 31] = fcW[idx];
    __syncthreads();
    if (t < 32) {  // c4 = b4 @ fcW + fcb
        float acc = fcb[t];
        for (int k = 0; k < 128; ++k) acc += b4[k] * Sa[k][t];
        cvec[96 + t] = acc;
    }
    {   // Sb = S3 = W4 @ fcW
        float a0 = 0.f, a1 = 0.f, a2 = 0.f, a3 = 0.f;
        for (int k = 0; k < 128; ++k) {
            float w = W4[i * 128 + k];
            a0 += w * Sa[k][j4 + 0]; a1 += w * Sa[k][j4 + 1];
            a2 += w * Sa[k][j4 + 2]; a3 += w * Sa[k][j4 + 3];
        }
        Sb[i][j4 + 0] = a0; Sb[i][j4 + 1] = a1; Sb[i][j4 + 2] = a2; Sb[i][j4 + 3] = a3;
    }
    __syncthreads();
    if (t < 32) {  // c3 = b3 @ S3
        float acc = 0.f;
        for (int k = 0; k < 128; ++k) acc += b3[k] * Sb[k][t];
        cvec[64 + t] = acc;
    }
    {   // Sa = S2 = W3 @ S3
        float a0 = 0.f, a1 = 0.f, a2 = 0.f, a3 = 0.f;
        for (int k = 0; k < 128; ++k) {
            float w = W3[i * 128 + k];
            a0 += w * Sb[k][j4 + 0]; a1 += w * Sb[k][j4 + 1];
            a2 += w * Sb[k][j4 + 2]; a3 += w * Sb[k][j4 + 3];
        }
        Sa[i][j4 + 0] = a0; Sa[i][j4 + 1] = a1; Sa[i][j4 + 2] = a2; Sa[i][j4 + 3] = a3;
    }
    __syncthreads();
    if (t < 32) {  // c2 = b2 @ S2
        float acc = 0.f;
        for (int k = 0; k < 128; ++k) acc += b2[k] * Sa[k][t];
        cvec[32 + t] = acc;
    }
    {   // Sb = S1 = W2 @ S2
        float a0 = 0.f, a1 = 0.f, a2 = 0.f, a3 = 0.f;
        for (int k = 0; k < 128; ++k) {
            float w = W2[i * 128 + k];
            a0 += w * Sa[k][j4 + 0]; a1 += w * Sa[k][j4 + 1];
            a2 += w * Sa[k][j4 + 2]; a3 += w * Sa[k][j4 + 3];
        }
        Sb[i][j4 + 0] = a0; Sb[i][j4 + 1] = a1; Sb[i][j4 + 2] = a2; Sb[i][j4 + 3] = a3;
    }
    __syncthreads();
    if (t < 32) {  // c1 = b1 @ S1
        float acc = 0.f;
        for (int k = 0; k < 128; ++k) acc += b1[k] * Sb[k][t];
        cvec[t] = acc;
    }
    {   // Wc = W1 @ S1 -> WcT[j][k] bf16
        float a0 = 0.f, a1 = 0.f, a2 = 0.f, a3 = 0.f;
        for (int k = 0; k < 128; ++k) {
            float w = W1[i * 128 + k];
            a0 += w * Sb[k][j4 + 0]; a1 += w * Sb[k][j4 + 1];
            a2 += w * Sb[k][j4 + 2]; a3 += w * Sb[k][j4 + 3];
        }
        WcT[(j4 + 0) * 128 + i] = (unsigned short)bf16rne(a0);
        WcT[(j4 + 1) * 128 + i] = (unsigned short)bf16rne(a1);
        WcT[(j4 + 2) * 128 + i] = (unsigned short)bf16rne(a2);
        WcT[(j4 + 3) * 128 + i] = (unsigned short)bf16rne(a3);
    }
}

__global__ __launch_bounds__(256) void scan_sum_kernel(const int* __restrict__ indeg,
                                                       int* __restrict__ bsum) {
    __shared__ int sdata[256];
    int blk = blockIdx.x, t = threadIdx.x;
    int i0 = blk * SCAN_B + t * 4;
    int v0 = (i0 + 0 < N_NODES) ? indeg[i0 + 0] : 0;
    int v1 = (i0 + 1 < N_NODES) ? indeg[i0 + 1] : 0;
    int v2 = (i0 + 2 < N_NODES) ? indeg[i0 + 2] : 0;
    int v3 = (i0 + 3 < N_NODES) ? indeg[i0 + 3] : 0;
    sdata[t] = v0 + v1 + v2 + v3;
    __syncthreads();
    for (int s = 128; s > 0; s >>= 1) {
        if (t < s) sdata[t] += sdata[t + s];
        __syncthreads();
    }
    if (t == 0) bsum[blk] = sdata[0];
}

// exclusive scan -> row_off + dinv + cursor zero.
__global__ void scanD_kernel(const int* __restrict__ indeg, const int* __restrict__ bsum,
                             int* __restrict__ row_off, float* __restrict__ dinv,
                             int* __restrict__ cursor) {
    __shared__ int sdata[257];
    int blk = blockIdx.x, t = threadIdx.x;
    int i0 = blk * SCAN_B + t * 4;
    int v0 = (i0 + 0 < N_NODES) ? indeg[i0 + 0] : 0;
    int v1 = (i0 + 1 < N_NODES) ? indeg[i0 + 1] : 0;
    int v2 = (i0 + 2 < N_NODES) ? indeg[i0 + 2] : 0;
    int v3 = (i0 + 3 < N_NODES) ? indeg[i0 + 3] : 0;
    int tsum = v0 + v1 + v2 + v3;
    if (t < 64) {
        int v = (t < blk) ? bsum[t] : 0;
#pragma unroll
        for (int off = 1; off < 64; off <<= 1) v += __shfl_xor(v, off, 64);
        if (t == 0) sdata[256] = v;
    }
    sdata[t] = tsum;
    __syncthreads();
    for (int off = 1; off < 256; off <<= 1) {
        int add = (t >= off) ? sdata[t - off] : 0;
        __syncthreads();
        sdata[t] += add;
        __syncthreads();
    }
    int base = sdata[256] + sdata[t] - tsum;
    if (i0 + 0 < N_NODES) { row_off[i0 + 0] = base;                dinv[i0 + 0] = rsqrtf((float)(v0 + 1)); cursor[i0 + 0] = 0; }
    if (i0 + 1 < N_NODES) { row_off[i0 + 1] = base + v0;           dinv[i0 + 1] = rsqrtf((float)(v1 + 1)); cursor[i0 + 1] = 0; }
    if (i0 + 2 < N_NODES) { row_off[i0 + 2] = base + v0 + v1;      dinv[i0 + 2] = rsqrtf((float)(v2 + 1)); cursor[i0 + 2] = 0; }
    if (i0 + 3 < N_NODES) { row_off[i0 + 3] = base + v0 + v1 + v2; dinv[i0 + 3] = rsqrtf((float)(v3 + 1)); cursor[i0 + 3] = 0; }
}

__global__ void fill_kernel(const int* __restrict__ src, const int* __restrict__ dst,
                            const int* __restrict__ row_off, int* __restrict__ cursor,
                            const float* __restrict__ dinv, int2* __restrict__ csr) {
    int e = blockIdx.x * blockDim.x + threadIdx.x;
    if (e >= N_EDGES) return;
    int d = dst[e], s = src[e];
    int pos = atomicAdd(&cursor[d], 1);
    csr[row_off[d] + pos] = make_int2(s, __float_as_int(dinv[s] * dinv[d]));
}

// ---------------- z = x @ Wc (f32 A -> bf16 MFMA, 32 cols) ----------------

__global__ __launch_bounds__(256) void gemm1_32_kernel(const float* __restrict__ A,
                                                       const unsigned short* __restrict__ WcT,
                                                       uint4* __restrict__ outb) {
    __shared__ unsigned short tile[4][16 * 32];
    int t = threadIdx.x;
    int wave = t >> 6, lane = t & 63;
    int row0 = blockIdx.x * 64 + wave * 16;
    int lm = lane & 15, lg = lane >> 4;

    int arow = row0 + lm;
    if (arow >= N_NODES) arow = N_NODES - 1;
    const float4* Arow = (const float4*)(A + (size_t)arow * 128);
    short8 a[4];
#pragma unroll
    for (int kc = 0; kc < 4; ++kc) {
        float4 f0 = Arow[kc * 8 + lg * 2];
        float4 f1 = Arow[kc * 8 + lg * 2 + 1];
        union { short8 s; uint4 u; } cvt;
        cvt.u = make_uint4(bf16pair(f0.x, f0.y), bf16pair(f0.z, f0.w),
                           bf16pair(f1.x, f1.y), bf16pair(f1.z, f1.w));
        a[kc] = cvt.s;
    }
    floatx4 acc[2];
#pragma unroll
    for (int i = 0; i < 2; ++i) acc[i] = (floatx4){0.f, 0.f, 0.f, 0.f};
#pragma unroll
    for (int nt = 0; nt < 2; ++nt) {
        const short8* Brow = (const short8*)(WcT + (size_t)(nt * 16 + lm) * 128);
#pragma unroll
        for (int kc = 0; kc < 4; ++kc)
            acc[nt] = __builtin_amdgcn_mfma_f32_16x16x32_bf16(a[kc], Brow[kc * 4 + lg],
                                                              acc[nt], 0, 0, 0);
    }
    unsigned short* T = tile[wave];
#pragma unroll
    for (int nt = 0; nt < 2; ++nt)
#pragma unroll
        for (int r = 0; r < 4; ++r)
            T[(lg * 4 + r) * 32 + nt * 16 + lm] = (unsigned short)bf16rne(acc[nt][r]);
    __syncthreads();
    int rr = lane >> 2, cseg = lane & 3;
    int orow = row0 + rr;
    uint4 v = *(const uint4*)&T[rr * 32 + cseg * 8];
    if (orow < N_NODES) outb[(size_t)orow * 4 + cseg] = v;
}

// ---------------- 32-dim aggregation, 4 edge-slots/quarter-wave/trip ----------------

// u_out = A u_in + 1 c^T, bf16 out (intermediate stages).
__global__ __launch_bounds__(256) void agg32b_kernel(const unsigned* __restrict__ Gb,
                                                     const float* __restrict__ bias,
                                                     const float* __restrict__ dinv,
                                                     const int* __restrict__ row_off,
                                                     const int* __restrict__ indeg,
                                                     const int2* __restrict__ csr,
                                                     unsigned* __restrict__ outb) {
    int wave = threadIdx.x >> 6;
    int lane = threadIdx.x & 63;
    int n = blockIdx.x * 4 + wave;  // N_NODES % 4 == 0
    int q = lane >> 4;
    int c = lane & 15;
    const unsigned hm = 0xffff0000u;

    float a0 = 0.f, a1 = 0.f;
    int beg = row_off[n];
    int end = beg + indeg[n];
    int e = beg + q;
    while (e < end) {
        int eA = e + 4, eB = e + 8, eC = e + 12;
        int2 c0 = csr[e];
        int2 c1 = csr[(eA < end) ? eA : e];
        int2 c2 = csr[(eB < end) ? eB : e];
        int2 c3 = csr[(eC < end) ? eC : e];
        float w0 = __int_as_float(c0.y);
        float w1 = (eA < end) ? __int_as_float(c1.y) : 0.f;
        float w2 = (eB < end) ? __int_as_float(c2.y) : 0.f;
        float w3 = (eC < end) ? __int_as_float(c3.y) : 0.f;
        unsigned r0 = Gb[c0.x * 16 + c];
        unsigned r1 = Gb[c1.x * 16 + c];
        unsigned r2 = Gb[c2.x * 16 + c];
        unsigned r3 = Gb[c3.x * 16 + c];
        a0 += w0 * __uint_as_float(r0 << 16) + w1 * __uint_as_float(r1 << 16) +
              w2 * __uint_as_float(r2 << 16) + w3 * __uint_as_float(r3 << 16);
        a1 += w0 * __uint_as_float(r0 & hm) + w1 * __uint_as_float(r1 & hm) +
              w2 * __uint_as_float(r2 & hm) + w3 * __uint_as_float(r3 & hm);
        e += 16;
    }
    a0 += __shfl_xor(a0, 16, 64); a0 += __shfl_xor(a0, 32, 64);
    a1 += __shfl_xor(a1, 16, 64); a1 += __shfl_xor(a1, 32, 64);
    if (q == 0) {
        float di = dinv[n];
        float sw = di * di;
        unsigned sv = Gb[n * 16 + c];
        a0 += sw * __uint_as_float(sv << 16);
        a1 += sw * __uint_as_float(sv & hm);
        float2 bb = ((const float2*)bias)[c];
        outb[(size_t)n * 16 + c] = bf16pair(a0 + bb.x, a1 + bb.y);
    }
}

// final stage: u4 = A u3 -> p fp32 (c4 folded into tail).
__global__ __launch_bounds__(256) void agg32_kernel(const unsigned* __restrict__ Gb,
                                                    const float* __restrict__ dinv,
                                                    const int* __restrict__ row_off,
                                                    const int* __restrict__ indeg,
                                                    const int2* __restrict__ csr,
                                                    float* __restrict__ p) {
    int wave = threadIdx.x >> 6;
    int lane = threadIdx.x & 63;
    int n = blockIdx.x * 4 + wave;
    int q = lane >> 4;
    int c = lane & 15;
    const unsigned hm = 0xffff0000u;

    float a0 = 0.f, a1 = 0.f;
    int beg = row_off[n];
    int end = beg + indeg[n];
    int e = beg + q;
    while (e < end) {
        int eA = e + 4, eB = e + 8, eC = e + 12;
        int2 c0 = csr[e];
        int2 c1 = csr[(eA < end) ? eA : e];
        int2 c2 = csr[(eB < end) ? eB : e];
        int2 c3 = csr[(eC < end) ? eC : e];
        float w0 = __int_as_float(c0.y);
        float w1 = (eA < end) ? __int_as_float(c1.y) : 0.f;
        float w2 = (eB < end) ? __int_as_float(c2.y) : 0.f;
        float w3 = (eC < end) ? __int_as_float(c3.y) : 0.f;
        unsigned r0 = Gb[c0.x * 16 + c];
        unsigned r1 = Gb[c1.x * 16 + c];
        unsigned r2 = Gb[c2.x * 16 + c];
        unsigned r3 = Gb[c3.x * 16 + c];
        a0 += w0 * __uint_as_float(r0 << 16) + w1 * __uint_as_float(r1 << 16) +
              w2 * __uint_as_float(r2 << 16) + w3 * __uint_as_float(r3 << 16);
        a1 += w0 * __uint_as_float(r0 & hm) + w1 * __uint_as_float(r1 & hm) +
              w2 * __uint_as_float(r2 & hm) + w3 * __uint_as_float(r3 & hm);
        e += 16;
    }
    a0 += __shfl_xor(a0, 16, 64); a0 += __shfl_xor(a0, 32, 64);
    a1 += __shfl_xor(a1, 16, 64); a1 += __shfl_xor(a1, 32, 64);
    if (q == 0) {
        float di = dinv[n];
        float sw = di * di;
        unsigned sv = Gb[n * 16 + c];
        a0 += sw * __uint_as_float(sv << 16);
        a1 += sw * __uint_as_float(sv & hm);
        ((float2*)p)[n * 16 + c] = make_float2(a0, a1);
    }
}

// ---------------- tail ----------------

__global__ __launch_bounds__(256) void tail_kernel(const float* __restrict__ p,
                                                   const int* __restrict__ batch,
                                                   const float* __restrict__ bc,
                                                   float* __restrict__ out) {
    __shared__ float partial[8][32];
    int g = blockIdx.x;
    int t = threadIdx.x;
    int rg = t >> 5, d = t & 31;
    int lo = 0, hi = N_NODES;
    while (lo < hi) { int m = (lo + hi) >> 1; if (batch[m] < g) lo = m + 1; else hi = m; }
    int lo2 = lo, hi2 = N_NODES;
    while (lo2 < hi2) { int m = (lo2 + hi2) >> 1; if (batch[m] < g + 1) lo2 = m + 1; else hi2 = m; }
    int cnt = lo2 - lo;
    float acc = 0.f;
    int n = lo + rg;
    for (; n + 24 < lo2; n += 32) {
        float u0 = p[n * 32 + d];
        float u1 = p[(n + 8) * 32 + d];
        float u2 = p[(n + 16) * 32 + d];
        float u3 = p[(n + 24) * 32 + d];
        acc += (u0 + u1) + (u2 + u3);
    }
    for (; n < lo2; n += 8) acc += p[n * 32 + d];
    partial[rg][d] = acc;
    __syncthreads();
    if (rg == 0) {
        float s = 0.f;
#pragma unroll
        for (int r = 0; r < 8; ++r) s += partial[r][d];
        out[g * 32 + d] = (cnt > 0) ? s / (float)cnt + bc[d] : 0.f;
    }
}

// ---------------- launch ----------------

static inline size_t align_up(size_t x) { return (x + 255) & ~(size_t)255; }

extern "C" void kernel_launch(void* const* d_in, const int* in_sizes, int n_in,
                              void* d_out, int out_size, void* d_ws, size_t ws_size,
                              hipStream_t stream) {
    const float* x = (const float*)d_in[0];
    const int* edge_index = (const int*)d_in[1];
    const int* batch = (const int*)d_in[2];
    const float* W1 = (const float*)d_in[3];
    const float* b1 = (const float*)d_in[4];
    const float* W2 = (const float*)d_in[5];
    const float* b2 = (const float*)d_in[6];
    const float* W3 = (const float*)d_in[7];
    const float* b3 = (const float*)d_in[8];
    const float* W4 = (const float*)d_in[9];
    const float* b4 = (const float*)d_in[10];
    const float* fcW = (const float*)d_in[11];
    const float* fcb = (const float*)d_in[12];
    float* out = (float*)d_out;

    const int* src = edge_index;
    const int* dst = edge_index + N_EDGES;

    char* base = (char*)d_ws;
    size_t o = 0;
    unsigned* buf0 = (unsigned*)(base + o); o = align_up(o + (size_t)N_NODES * D_OUT * 2);
    unsigned* buf1 = (unsigned*)(base + o); o = align_up(o + (size_t)N_NODES * D_OUT * 2);
    int2* csr = (int2*)(base + o);          o = align_up(o + (size_t)N_EDGES * 8);
    int* row_off = (int*)(base + o);        o = align_up(o + (size_t)N_NODES * 4);
    int* indeg = (int*)(base + o);          o = align_up(o + (size_t)N_NODES * 4);
    int* cursor = (int*)(base + o);         o = align_up(o + (size_t)N_NODES * 4);
    float* dinv = (float*)(base + o);       o = align_up(o + (size_t)N_NODES * 4);
    int* bsum = (int*)(base + o);           o = align_up(o + 256);
    unsigned short* WcT = (unsigned short*)(base + o); o = align_up(o + (size_t)D * D_OUT * 2);
    float* cvec = (float*)(base + o);       o = align_up(o + 128 * 4);
    float* p = (float*)(base + o);          o = align_up(o + (size_t)N_NODES * D_OUT * 4);

    hipMemsetAsync(indeg, 0, (size_t)N_NODES * 4, stream);
    hist_kernel<<<(N_EDGES + 255) / 256, 256, 0, stream>>>(dst, indeg);
    collapse_kernel<<<1, 1024, 0, stream>>>(W1, W2, W3, W4, fcW, fcb, b1, b2, b3, b4,
                                            WcT, cvec);
    scan_sum_kernel<<<N_SCAN_BLOCKS, 256, 0, stream>>>(indeg, bsum);
    scanD_kernel<<<N_SCAN_BLOCKS, 256, 0, stream>>>(indeg, bsum, row_off, dinv, cursor);
    fill_kernel<<<(N_EDGES + 255) / 256, 256, 0, stream>>>(src, dst, row_off, cursor,
                                                           dinv, csr);

    gemm1_32_kernel<<<GEMM_BLOCKS, 256, 0, stream>>>(x, WcT, (uint4*)buf0);
    agg32b_kernel<<<AGG_GRID, 256, 0, stream>>>(buf0, cvec + 0, dinv, row_off, indeg,
                                                csr, buf1);
    agg32b_kernel<<<AGG_GRID, 256, 0, stream>>>(buf1, cvec + 32, dinv, row_off, indeg,
                                                csr, buf0);
    agg32b_kernel<<<AGG_GRID, 256, 0, stream>>>(buf0, cvec + 64, dinv, row_off, indeg,
                                                csr, buf1);
    agg32_kernel<<<AGG_GRID, 256, 0, stream>>>(buf1, dinv, row_off, indeg, csr, p);
    tail_kernel<<<N_GRAPHS, 256, 0, stream>>>(p, batch, cvec + 96, out);
}